// Round 3
// baseline (325.196 us; speedup 1.0000x reference)
//
#include <hip/hip_runtime.h>
#include <stdint.h>

typedef __bf16 bf16_t;
typedef bf16_t bf16x8 __attribute__((ext_vector_type(8)));
typedef float f32x4 __attribute__((ext_vector_type(4)));

// ---------- helpers ----------

__device__ __forceinline__ uint16_t f2bf(float f) {
    uint32_t u = __float_as_uint(f);
    u += 0x7FFFu + ((u >> 16) & 1u);   // RNE
    return (uint16_t)(u >> 16);
}

__device__ __forceinline__ f32x4 mfma16(bf16x8 a, bf16x8 b, f32x4 c) {
    return __builtin_amdgcn_mfma_f32_16x16x32_bf16(a, b, c, 0, 0, 0);
}

// read one 16B MFMA fragment from a [rows][64] bf16 LDS tile with XOR swizzle
__device__ __forceinline__ bf16x8 lds_frag(const uint16_t* smem, int row, int kbyte) {
    int off = row * 128 + (kbyte ^ ((row & 7) << 4));
    return __builtin_bit_cast(bf16x8,
        *reinterpret_cast<const uint4*>(reinterpret_cast<const char*>(smem) + off));
}

// stage a ROWS x 64 bf16 tile into LDS with XOR swizzle (reg-staged)
template <int ROWS>
__device__ __forceinline__ void stage_tile(uint16_t* lds, const uint16_t* src,
                                           int src_stride, int tid) {
    constexpr int CH  = ROWS * 8;     // 16B chunks
    constexpr int PER = CH / 256;
#pragma unroll
    for (int i = 0; i < PER; ++i) {
        int c   = tid + i * 256;
        int row = c >> 3, cc = c & 7;
        uint4 v = *reinterpret_cast<const uint4*>(src + (size_t)row * src_stride + cc * 8);
        int off = row * 128 + ((cc * 16) ^ ((row & 7) << 4));
        *reinterpret_cast<uint4*>(reinterpret_cast<char*>(lds) + off) = v;
    }
}

// ---------- kernel 0: adj dtype detect ----------
// mode 0: int32 {0,1}; mode 1: float32 {0.0,1.0}; mode 2: bytes
__global__ void detect_kernel(const unsigned int* __restrict__ adj, int* __restrict__ flag) {
    __shared__ int notint, notf32;
    if (threadIdx.x == 0) { notint = 0; notf32 = 0; }
    __syncthreads();
    int ni = 0, nf = 0;
    for (int i = threadIdx.x; i < 4096; i += 256) {
        unsigned v = adj[i];
        if (v > 1u) ni = 1;
        if (v != 0u && v != 0x3f800000u) nf = 1;
    }
    if (ni) notint = 1;
    if (nf) notf32 = 1;
    __syncthreads();
    if (threadIdx.x == 0) *flag = notint ? (notf32 ? 2 : 1) : 0;
}

// ---------- kernel 1: fp32 -> bf16 convert (x + 4 weights) ----------
__global__ void convert_kernel(const float* __restrict__ x, const float* __restrict__ wq,
                               const float* __restrict__ wk, const float* __restrict__ wv,
                               const float* __restrict__ wo,
                               uint16_t* __restrict__ xb, uint16_t* __restrict__ wqb,
                               uint16_t* __restrict__ wkb, uint16_t* __restrict__ wvb,
                               uint16_t* __restrict__ wob) {
    int i = blockIdx.x * 256 + threadIdx.x;   // float4 index
    const float* src; uint16_t* dst; int idx;
    if (i < 2097152) { src = x; dst = xb; idx = i; }
    else {
        int wi = i - 2097152;
        int which = wi >> 16; idx = wi & 65535;
        src = which == 0 ? wq : which == 1 ? wk : which == 2 ? wv : wo;
        dst = which == 0 ? wqb : which == 1 ? wkb : which == 2 ? wvb : wob;
    }
    float4 v = reinterpret_cast<const float4*>(src)[idx];
    ushort4 o;
    o.x = f2bf(v.x); o.y = f2bf(v.y); o.z = f2bf(v.z); o.w = f2bf(v.w);
    reinterpret_cast<ushort4*>(dst)[idx] = o;
}

// ---------- GEMM template ----------
// C[m][c] = sum_k A[m][k] * B[c][k]  (+bias)   A:[M][512] bf16, B:[512][512] bf16
// MODE 0: QKV -> write q/k [B,H,N,64] bf16, v transposed [B,H,64,N] bf16
// MODE 1: out projection -> fp32 [M][512] + bias
template <int MODE>
__launch_bounds__(256)
__global__ void gemm_kernel(const uint16_t* __restrict__ A,
                            const uint16_t* __restrict__ B0, const uint16_t* __restrict__ B1,
                            const uint16_t* __restrict__ B2,
                            const float* __restrict__ bias0, const float* __restrict__ bias1,
                            const float* __restrict__ bias2,
                            uint16_t* __restrict__ qws, uint16_t* __restrict__ kws,
                            uint16_t* __restrict__ vws, float* __restrict__ outf) {
    __shared__ uint16_t As[128 * 64];
    __shared__ uint16_t Bs[128 * 64];
    const int tid  = threadIdx.x;
    const int lane = tid & 63;
    const int wid  = tid >> 6;
    const int wm   = wid >> 1, wn = wid & 1;
    const int m0   = blockIdx.y * 128;
    const int n0   = blockIdx.x * 128;
    const int sel  = n0 >> 9;
    const int nw   = n0 & 511;
    const uint16_t* Bsrc = (MODE == 0) ? (sel == 0 ? B0 : sel == 1 ? B1 : B2) : B0;
    const int fr = lane & 15, fq = lane >> 4;

    f32x4 acc[4][4];
#pragma unroll
    for (int a = 0; a < 4; ++a)
#pragma unroll
        for (int b = 0; b < 4; ++b) acc[a][b] = (f32x4){0.f, 0.f, 0.f, 0.f};

    for (int k0 = 0; k0 < 512; k0 += 64) {
        __syncthreads();
        stage_tile<128>(As, A + (size_t)m0 * 512 + k0, 512, tid);
        stage_tile<128>(Bs, Bsrc + (size_t)nw * 512 + k0, 512, tid);
        __syncthreads();
#pragma unroll
        for (int ks = 0; ks < 2; ++ks) {
            int kb = ks * 64 + fq * 16;
            bf16x8 af[4], bfr[4];
#pragma unroll
            for (int i = 0; i < 4; ++i) af[i]  = lds_frag(As, wm * 64 + i * 16 + fr, kb);
#pragma unroll
            for (int i = 0; i < 4; ++i) bfr[i] = lds_frag(Bs, wn * 64 + i * 16 + fr, kb);
#pragma unroll
            for (int mf = 0; mf < 4; ++mf)
#pragma unroll
                for (int nf = 0; nf < 4; ++nf)
                    acc[mf][nf] = mfma16(af[mf], bfr[nf], acc[mf][nf]);
        }
    }

    if (MODE == 0) {
        const float* bias = sel == 0 ? bias0 : sel == 1 ? bias1 : bias2;
#pragma unroll
        for (int nf = 0; nf < 4; ++nf) {
            int c  = nw + wn * 64 + nf * 16 + fr;   // col within this weight [0,512)
            float bv = bias[c];
            int h = c >> 6, dh = c & 63;
#pragma unroll
            for (int mf = 0; mf < 4; ++mf) {
                int mbase = m0 + wm * 64 + mf * 16 + fq * 4;
                int b  = mbase >> 9;
                int ns = mbase & 511;
                if (sel < 2) {
                    uint16_t* dst = (sel == 0 ? qws : kws);
                    size_t base = ((size_t)(b * 8 + h) * 512) * 64;
#pragma unroll
                    for (int j = 0; j < 4; ++j)
                        dst[base + (size_t)(ns + j) * 64 + dh] = f2bf(acc[mf][nf][j] + bv);
                } else {
                    ushort4 pk;
                    pk.x = f2bf(acc[mf][nf][0] + bv);
                    pk.y = f2bf(acc[mf][nf][1] + bv);
                    pk.z = f2bf(acc[mf][nf][2] + bv);
                    pk.w = f2bf(acc[mf][nf][3] + bv);
                    *reinterpret_cast<ushort4*>(
                        &vws[((size_t)(b * 8 + h) * 64 + dh) * 512 + ns]) = pk;
                }
            }
        }
    } else {
#pragma unroll
        for (int nf = 0; nf < 4; ++nf) {
            int c = n0 + wn * 64 + nf * 16 + fr;
            float bv = bias0[c];
#pragma unroll
            for (int mf = 0; mf < 4; ++mf) {
                int mbase = m0 + wm * 64 + mf * 16 + fq * 4;
#pragma unroll
                for (int j = 0; j < 4; ++j)
                    outf[(size_t)(mbase + j) * 512 + c] = acc[mf][nf][j] + bv;
            }
        }
    }
}

// ---------- kernel 3: masked flash attention ----------
// grid: B*H*8 blocks; 4 waves, each owns 16 q-rows of a 64-row q-tile
__launch_bounds__(256)
__global__ void attn_kernel(const uint16_t* __restrict__ qws, const uint16_t* __restrict__ kws,
                            const uint16_t* __restrict__ vws, const void* __restrict__ adj,
                            const int* __restrict__ mode_flag, uint16_t* __restrict__ ows) {
    __shared__ uint16_t Ks[64 * 64];
    __shared__ uint16_t Vs[64 * 64];   // V^T tile: rows = d, cols = kv
    __shared__ uint16_t Ps[4 * 16 * 64];
    const int tid = threadIdx.x, lane = tid & 63, w = tid >> 6;
    const int bx = blockIdx.x;
    const int qt = bx & 7, h = (bx >> 3) & 7, b = bx >> 6;
    const int mode = *mode_flag;
    const size_t qk_head = (size_t)(b * 8 + h) * 512 * 64;
    const size_t v_head  = (size_t)(b * 8 + h) * 64 * 512;
    const int fr = lane & 15, fq = lane >> 4;
    const int qr0 = qt * 64 + w * 16;

    bf16x8 aq[2];
#pragma unroll
    for (int ks = 0; ks < 2; ++ks)
        aq[ks] = __builtin_bit_cast(bf16x8,
            *reinterpret_cast<const uint4*>(qws + qk_head + (size_t)(qr0 + fr) * 64 + ks * 32 + fq * 8));

    float mrun[4], lsum[4];
    f32x4 oacc[4];
#pragma unroll
    for (int j = 0; j < 4; ++j) { mrun[j] = -1e30f; lsum[j] = 0.f; }
#pragma unroll
    for (int nf = 0; nf < 4; ++nf) oacc[nf] = (f32x4){0.f, 0.f, 0.f, 0.f};

    const float LOG2E = 1.4426950408889634f;

    for (int kt = 0; kt < 8; ++kt) {
        __syncthreads();
        stage_tile<64>(Ks, kws + qk_head + (size_t)kt * 64 * 64, 64, tid);
        stage_tile<64>(Vs, vws + v_head + (size_t)kt * 64, 512, tid);
        __syncthreads();

        // S = Q K^T
        f32x4 sacc[4];
#pragma unroll
        for (int nf = 0; nf < 4; ++nf) sacc[nf] = (f32x4){0.f, 0.f, 0.f, 0.f};
#pragma unroll
        for (int ks = 0; ks < 2; ++ks) {
            int kb = ks * 64 + fq * 16;
#pragma unroll
            for (int nf = 0; nf < 4; ++nf) {
                bf16x8 bk = lds_frag(Ks, nf * 16 + fr, kb);
                sacc[nf] = mfma16(aq[ks], bk, sacc[nf]);
            }
        }

        // scale + mask
        float s[4][4];
#pragma unroll
        for (int nf = 0; nf < 4; ++nf) {
            int kg = kt * 64 + nf * 16 + fr;
#pragma unroll
            for (int j = 0; j < 4; ++j) {
                int qg = qt * 64 + w * 16 + fq * 4 + j;
                bool ok;
                if (mode == 0)      ok = reinterpret_cast<const int*>(adj)[qg * 512 + kg] != 0;
                else if (mode == 1) ok = reinterpret_cast<const float*>(adj)[qg * 512 + kg] != 0.0f;
                else                ok = reinterpret_cast<const unsigned char*>(adj)[qg * 512 + kg] != 0;
                s[nf][j] = ok ? sacc[nf][j] * 0.125f : -1e30f;
            }
        }

        // online softmax update
        float fsc[4];
#pragma unroll
        for (int j = 0; j < 4; ++j) {
            float t = fmaxf(fmaxf(s[0][j], s[1][j]), fmaxf(s[2][j], s[3][j]));
            t = fmaxf(t, __shfl_xor(t, 1));
            t = fmaxf(t, __shfl_xor(t, 2));
            t = fmaxf(t, __shfl_xor(t, 4));
            t = fmaxf(t, __shfl_xor(t, 8));
            float mn = fmaxf(mrun[j], t);
            fsc[j] = exp2f((mrun[j] - mn) * LOG2E);
            mrun[j] = mn;
        }
        float rs[4] = {0.f, 0.f, 0.f, 0.f};
#pragma unroll
        for (int nf = 0; nf < 4; ++nf)
#pragma unroll
            for (int j = 0; j < 4; ++j) {
                float p = exp2f((s[nf][j] - mrun[j]) * LOG2E);
                s[nf][j] = p;
                rs[j] += p;
            }
#pragma unroll
        for (int j = 0; j < 4; ++j) {
            float r = rs[j];
            r += __shfl_xor(r, 1);
            r += __shfl_xor(r, 2);
            r += __shfl_xor(r, 4);
            r += __shfl_xor(r, 8);
            lsum[j] = lsum[j] * fsc[j] + r;
        }
#pragma unroll
        for (int nf = 0; nf < 4; ++nf)
#pragma unroll
            for (int j = 0; j < 4; ++j) oacc[nf][j] *= fsc[j];

        // P -> LDS (per-wave region, swizzled)
        uint16_t* pw = Ps + w * 16 * 64;
#pragma unroll
        for (int nf = 0; nf < 4; ++nf)
#pragma unroll
            for (int j = 0; j < 4; ++j) {
                int rp = fq * 4 + j, cp = nf * 16 + fr;
                int off = rp * 128 + ((cp * 2) ^ ((rp & 7) << 4));
                *reinterpret_cast<uint16_t*>(reinterpret_cast<char*>(pw) + off) = f2bf(s[nf][j]);
            }

        // O += P V
#pragma unroll
        for (int ks = 0; ks < 2; ++ks) {
            int kb = ks * 64 + fq * 16;
            bf16x8 ap = lds_frag(pw, fr, kb);
#pragma unroll
            for (int nf = 0; nf < 4; ++nf) {
                bf16x8 bv = lds_frag(Vs, nf * 16 + fr, kb);
                oacc[nf] = mfma16(ap, bv, oacc[nf]);
            }
        }
    }

    // epilogue: divide and store o [B,N,H,64] bf16
#pragma unroll
    for (int nf = 0; nf < 4; ++nf) {
        int d = nf * 16 + fr;
#pragma unroll
        for (int j = 0; j < 4; ++j) {
            int n = qt * 64 + w * 16 + fq * 4 + j;
            float v = oacc[nf][j] / lsum[j];
            ows[((size_t)(b * 512 + n) * 8 + h) * 64 + d] = f2bf(v);
        }
    }
}

// ---------- launch ----------
extern "C" void kernel_launch(void* const* d_in, const int* in_sizes, int n_in,
                              void* d_out, int out_size, void* d_ws, size_t ws_size,
                              hipStream_t stream) {
    const float* x  = (const float*)d_in[0];
    const void*  adj = d_in[1];
    const float* Wq = (const float*)d_in[2];
    const float* Wk = (const float*)d_in[3];
    const float* Wv = (const float*)d_in[4];
    const float* bq = (const float*)d_in[5];
    const float* bk = (const float*)d_in[6];
    const float* bv = (const float*)d_in[7];
    const float* Wo = (const float*)d_in[8];
    const float* bo = (const float*)d_in[9];
    float* out = (float*)d_out;

    char* p = (char*)d_ws;
    uint16_t* xb  = (uint16_t*)p; p += (size_t)8388608 * 2;   // also reused as ows
    uint16_t* wqb = (uint16_t*)p; p += 262144 * 2;
    uint16_t* wkb = (uint16_t*)p; p += 262144 * 2;
    uint16_t* wvb = (uint16_t*)p; p += 262144 * 2;
    uint16_t* wob = (uint16_t*)p; p += 262144 * 2;
    uint16_t* qws = (uint16_t*)p; p += (size_t)8388608 * 2;
    uint16_t* kws = (uint16_t*)p; p += (size_t)8388608 * 2;
    uint16_t* vws = (uint16_t*)p; p += (size_t)8388608 * 2;
    int* flag = (int*)p;
    uint16_t* ows = xb;   // xb dead after QKV GEMM

    detect_kernel<<<1, 256, 0, stream>>>((const unsigned int*)adj, flag);
    convert_kernel<<<9216, 256, 0, stream>>>(x, Wq, Wk, Wv, Wo, xb, wqb, wkb, wvb, wob);
    dim3 g1(12, 128);
    gemm_kernel<0><<<g1, 256, 0, stream>>>(xb, wqb, wkb, wvb, bq, bk, bv,
                                           qws, kws, vws, nullptr);
    attn_kernel<<<2048, 256, 0, stream>>>(qws, kws, vws, adj, flag, ows);
    dim3 g2(4, 128);
    gemm_kernel<1><<<g2, 256, 0, stream>>>(ows, wob, wob, wob, bo, bo, bo,
                                           nullptr, nullptr, nullptr, out);
}